// Round 1
// baseline (117.560 us; speedup 1.0000x reference)
//
#include <hip/hip_runtime.h>
#include <hip/hip_bf16.h>

typedef __attribute__((ext_vector_type(8))) short bf16x8;
typedef __attribute__((ext_vector_type(4))) float f32x4;

#define K_DIM 256
#define N_DIM 512
#define BM 64
#define M_DIM 65536

// round-to-nearest-even fp32 -> bf16 bits
__device__ __forceinline__ unsigned short f2bf(float f) {
    unsigned int u = __float_as_uint(f);
    unsigned int r = (u + 0x7fffu + ((u >> 16) & 1u)) >> 16;
    return (unsigned short)r;
}

// Kernel 1: clusters fp32 -> bf16 (for MFMA) + fp32 row norms.
__global__ __launch_bounds__(256) void prep_clusters(
        const float* __restrict__ clusters,
        unsigned short* __restrict__ cb,
        float* __restrict__ csq) {
    const int row = blockIdx.x;   // 512 rows
    const int t = threadIdx.x;    // 256 = K_DIM
    const float v = clusters[row * K_DIM + t];
    cb[row * K_DIM + t] = f2bf(v);
    float s = v * v;
    #pragma unroll
    for (int m = 1; m < 64; m <<= 1) s += __shfl_xor(s, m);
    __shared__ float red[4];
    if ((t & 63) == 0) red[t >> 6] = s;
    __syncthreads();
    if (t == 0) csq[row] = red[0] + red[1] + red[2] + red[3];
}

// Kernel 2: fused  cross-GEMM (bf16 MFMA) + student-t + row normalize.
// Block = 64 rows x ALL 512 cols. 8 waves in a 2(M) x 4(N) grid;
// each wave: 32 rows x 128 cols = 2 x 8 fragments of 16x16.
__global__ __launch_bounds__(512) void cluster_q(
        const float* __restrict__ x,
        const unsigned short* __restrict__ cb,
        const float* __restrict__ csq,
        float* __restrict__ out) {
    __shared__ __align__(16) unsigned short xa[BM * K_DIM]; // 32 KB bf16, XOR-swizzled
    __shared__ float xsq[BM];
    __shared__ float csql[N_DIM];
    __shared__ float rsum[4][BM];

    const int t = threadIdx.x;
    const int lane = t & 63;
    const int wave = t >> 6;      // 0..7
    const int wr = wave >> 2;     // 0..1 (M)
    const int wc = wave & 3;      // 0..3 (N)
    const int rowbase = blockIdx.x * BM;

    // stage cluster norms (broadcast data, L2-resident)
    for (int i = t; i < N_DIM; i += 512) csql[i] = csq[i];

    // stage x tile: wave w loads full row (w + 8p) as float4 (coalesced 1 KB/row),
    // computes |x|^2 via wave reduce, stores bf16 swizzled.
    #pragma unroll
    for (int p = 0; p < 8; ++p) {
        const int row = wave + p * 8;
        const float4 v = reinterpret_cast<const float4*>(
                             x + (size_t)(rowbase + row) * K_DIM)[lane];
        float s = v.x * v.x + v.y * v.y + v.z * v.z + v.w * v.w;
        #pragma unroll
        for (int m = 1; m < 64; m <<= 1) s += __shfl_xor(s, m);
        if (lane == 0) xsq[row] = s;
        const ushort4 pk = make_ushort4(f2bf(v.x), f2bf(v.y), f2bf(v.z), f2bf(v.w));
        const int swz = (lane * 8) ^ ((row & 7) << 4);   // bank-conflict swizzle
        *reinterpret_cast<ushort4*>(reinterpret_cast<char*>(xa) + row * 512 + swz) = pk;
    }
    __syncthreads();

    f32x4 acc[2][8];
    #pragma unroll
    for (int m = 0; m < 2; ++m)
        #pragma unroll
        for (int n = 0; n < 8; ++n)
            acc[m][n] = (f32x4){0.f, 0.f, 0.f, 0.f};

    // K loop: A from swizzled LDS, B straight from L2-resident bf16 clusters.
    #pragma unroll
    for (int ks = 0; ks < 8; ++ks) {
        const int k0 = ks * 32;
        bf16x8 a[2];
        #pragma unroll
        for (int m = 0; m < 2; ++m) {
            const int row = wr * 32 + m * 16 + (lane & 15);
            const int cswz = (k0 * 2 + (lane >> 4) * 16) ^ ((row & 7) << 4);
            a[m] = *reinterpret_cast<const bf16x8*>(
                       reinterpret_cast<const char*>(xa) + row * 512 + cswz);
        }
        #pragma unroll
        for (int n = 0; n < 8; ++n) {
            const int col = wc * 128 + n * 16 + (lane & 15);
            const bf16x8 b = *reinterpret_cast<const bf16x8*>(
                cb + (size_t)col * K_DIM + k0 + (lane >> 4) * 8);
            acc[0][n] = __builtin_amdgcn_mfma_f32_16x16x32_bf16(a[0], b, acc[0][n], 0, 0, 0);
            acc[1][n] = __builtin_amdgcn_mfma_f32_16x16x32_bf16(a[1], b, acc[1][n], 0, 0, 0);
        }
    }

    // epilogue: d = |x|^2 + |c|^2 - 2*cross ; q_un = 1/(1+d) (ALPHA=1)
    float part[2][4];
    #pragma unroll
    for (int m = 0; m < 2; ++m)
        #pragma unroll
        for (int j = 0; j < 4; ++j) part[m][j] = 0.f;

    #pragma unroll
    for (int m = 0; m < 2; ++m) {
        #pragma unroll
        for (int n = 0; n < 8; ++n) {
            const int col = wc * 128 + n * 16 + (lane & 15);
            const float cs = csql[col];
            #pragma unroll
            for (int j = 0; j < 4; ++j) {
                const int rloc = wr * 32 + m * 16 + (lane >> 4) * 4 + j;
                const float d = xsq[rloc] + cs - 2.f * acc[m][n][j];
                const float q = 1.f / (1.f + d);
                acc[m][n][j] = q;
                part[m][j] += q;
            }
        }
    }

    // row sums: 16-lane butterfly (cols within wave) then cross-wave via LDS
    #pragma unroll
    for (int m = 0; m < 2; ++m)
        #pragma unroll
        for (int j = 0; j < 4; ++j) {
            float s = part[m][j];
            s += __shfl_xor(s, 1);
            s += __shfl_xor(s, 2);
            s += __shfl_xor(s, 4);
            s += __shfl_xor(s, 8);
            if ((lane & 15) == 0)
                rsum[wc][wr * 32 + m * 16 + (lane >> 4) * 4 + j] = s;
        }
    __syncthreads();

    // normalize + store (16 lanes = 64B contiguous per row segment)
    #pragma unroll
    for (int m = 0; m < 2; ++m) {
        #pragma unroll
        for (int j = 0; j < 4; ++j) {
            const int rloc = wr * 32 + m * 16 + (lane >> 4) * 4 + j;
            const float inv = 1.f / (rsum[0][rloc] + rsum[1][rloc] +
                                     rsum[2][rloc] + rsum[3][rloc]);
            float* orow = out + (size_t)(rowbase + rloc) * N_DIM;
            #pragma unroll
            for (int n = 0; n < 8; ++n)
                orow[wc * 128 + n * 16 + (lane & 15)] = acc[m][n][j] * inv;
        }
    }
}

extern "C" void kernel_launch(void* const* d_in, const int* in_sizes, int n_in,
                              void* d_out, int out_size, void* d_ws, size_t ws_size,
                              hipStream_t stream) {
    const float* x        = (const float*)d_in[0];
    const float* clusters = (const float*)d_in[1];
    float* out = (float*)d_out;
    unsigned short* cb = (unsigned short*)d_ws;                       // 512*256 bf16 = 256 KB
    float* csq = (float*)((char*)d_ws + (size_t)N_DIM * K_DIM * 2);   // + 2 KB
    prep_clusters<<<N_DIM, K_DIM, 0, stream>>>(clusters, cb, csq);
    cluster_q<<<M_DIM / BM, 512, 0, stream>>>(x, cb, csq, out);
}

// Round 2
// 98.935 us; speedup vs baseline: 1.1883x; 1.1883x over previous
//
#include <hip/hip_runtime.h>
#include <hip/hip_bf16.h>

typedef __attribute__((ext_vector_type(8))) short bf16x8;
typedef __attribute__((ext_vector_type(4))) float f32x4;

#define K_DIM 256
#define N_DIM 512
#define BM 32
#define M_DIM 65536

// round-to-nearest-even fp32 -> bf16 bits
__device__ __forceinline__ unsigned short f2bf(float f) {
    unsigned int u = __float_as_uint(f);
    unsigned int r = (u + 0x7fffu + ((u >> 16) & 1u)) >> 16;
    return (unsigned short)r;
}

// Kernel 1: clusters fp32 -> bf16 (for MFMA) + fp32 row norms.
__global__ __launch_bounds__(256) void prep_clusters(
        const float* __restrict__ clusters,
        unsigned short* __restrict__ cb,
        float* __restrict__ csq) {
    const int row = blockIdx.x;   // 512 rows
    const int t = threadIdx.x;    // 256 = K_DIM
    const float v = clusters[row * K_DIM + t];
    cb[row * K_DIM + t] = f2bf(v);
    float s = v * v;
    #pragma unroll
    for (int m = 1; m < 64; m <<= 1) s += __shfl_xor(s, m);
    __shared__ float red[4];
    if ((t & 63) == 0) red[t >> 6] = s;
    __syncthreads();
    if (t == 0) csq[row] = red[0] + red[1] + red[2] + red[3];
}

// Kernel 2: fused cross-GEMM (bf16 MFMA) + student-t + row normalize.
// Block = 32 rows x ALL 512 cols, 4 waves (one per 128-col group).
// Each wave: 2 (M) x 8 (N) fragments of 16x16, K=256 in 8 steps of 32.
// B fragments prefetched one full K-step ahead (8 loads in flight/wave).
__global__ __launch_bounds__(256, 3) void cluster_q(
        const float* __restrict__ x,
        const unsigned short* __restrict__ cb,
        const float* __restrict__ csq,
        float* __restrict__ out) {
    __shared__ __align__(16) unsigned short xa[BM * K_DIM]; // 16 KB bf16, XOR-swizzled
    __shared__ float xsq[BM];
    __shared__ float csql[N_DIM];
    __shared__ float rsum[4][BM];

    const int t = threadIdx.x;
    const int lane = t & 63;
    const int wc = t >> 6;        // wave 0..3 = column group
    const int rowbase = blockIdx.x * BM;

    // stage cluster norms (L2-resident broadcast data)
    for (int i = t; i < N_DIM; i += 256) csql[i] = csq[i];

    // stage x tile: wave w loads rows w+4p as float4 (1 KB/row coalesced),
    // |x|^2 via wave reduce, bf16 store XOR-swizzled.
    #pragma unroll
    for (int p = 0; p < 8; ++p) {
        const int row = wc + p * 4;
        const float4 v = reinterpret_cast<const float4*>(
                             x + (size_t)(rowbase + row) * K_DIM)[lane];
        float s = v.x * v.x + v.y * v.y + v.z * v.z + v.w * v.w;
        #pragma unroll
        for (int m = 1; m < 64; m <<= 1) s += __shfl_xor(s, m);
        if (lane == 0) xsq[row] = s;
        const ushort4 pk = make_ushort4(f2bf(v.x), f2bf(v.y), f2bf(v.z), f2bf(v.w));
        const int swz = (lane * 8) ^ ((row & 7) << 4);
        *reinterpret_cast<ushort4*>(reinterpret_cast<char*>(xa) + row * 512 + swz) = pk;
    }
    __syncthreads();

    f32x4 acc[2][8];
    #pragma unroll
    for (int m = 0; m < 2; ++m)
        #pragma unroll
        for (int n = 0; n < 8; ++n)
            acc[m][n] = (f32x4){0.f, 0.f, 0.f, 0.f};

    // B fragment base for this lane: col = wc*128 + (lane&15), k-half = (lane>>4)*8
    const unsigned short* bbase =
        cb + (size_t)(wc * 128 + (lane & 15)) * K_DIM + (lane >> 4) * 8;

    // preload ks=0 fragments
    bf16x8 b[8];
    #pragma unroll
    for (int n = 0; n < 8; ++n)
        b[n] = *reinterpret_cast<const bf16x8*>(bbase + n * 16 * K_DIM);

    #pragma unroll
    for (int ks = 0; ks < 8; ++ks) {
        // issue next K-step's B loads first (8 in flight across this step's MFMAs)
        bf16x8 bn[8];
        if (ks < 7) {
            #pragma unroll
            for (int n = 0; n < 8; ++n)
                bn[n] = *reinterpret_cast<const bf16x8*>(
                            bbase + n * 16 * K_DIM + (ks + 1) * 32);
        }
        // A fragments from swizzled LDS
        bf16x8 a0, a1;
        {
            const int r0 = (lane & 15);
            const int r1 = 16 + (lane & 15);
            const int c0 = (ks * 64 + (lane >> 4) * 16) ^ ((r0 & 7) << 4);
            const int c1 = (ks * 64 + (lane >> 4) * 16) ^ ((r1 & 7) << 4);
            a0 = *reinterpret_cast<const bf16x8*>(
                     reinterpret_cast<const char*>(xa) + r0 * 512 + c0);
            a1 = *reinterpret_cast<const bf16x8*>(
                     reinterpret_cast<const char*>(xa) + r1 * 512 + c1);
        }
        #pragma unroll
        for (int n = 0; n < 8; ++n) {
            acc[0][n] = __builtin_amdgcn_mfma_f32_16x16x32_bf16(a0, b[n], acc[0][n], 0, 0, 0);
            acc[1][n] = __builtin_amdgcn_mfma_f32_16x16x32_bf16(a1, b[n], acc[1][n], 0, 0, 0);
        }
        if (ks < 7) {
            #pragma unroll
            for (int n = 0; n < 8; ++n) b[n] = bn[n];
        }
    }

    // epilogue: d = |x|^2 + |c|^2 - 2*cross ; q_un = 1/(1+d) (ALPHA=1)
    float xs1[2][4];
    #pragma unroll
    for (int m = 0; m < 2; ++m)
        #pragma unroll
        for (int j = 0; j < 4; ++j)
            xs1[m][j] = 1.f + xsq[m * 16 + (lane >> 4) * 4 + j];

    float part[2][4];
    #pragma unroll
    for (int m = 0; m < 2; ++m)
        #pragma unroll
        for (int j = 0; j < 4; ++j) part[m][j] = 0.f;

    #pragma unroll
    for (int m = 0; m < 2; ++m) {
        #pragma unroll
        for (int n = 0; n < 8; ++n) {
            const float cs = csql[wc * 128 + n * 16 + (lane & 15)];
            #pragma unroll
            for (int j = 0; j < 4; ++j) {
                const float q = __builtin_amdgcn_rcpf(
                                    fmaf(-2.f, acc[m][n][j], xs1[m][j] + cs));
                acc[m][n][j] = q;
                part[m][j] += q;
            }
        }
    }

    // row sums: 16-lane butterfly (cols within wave) then cross-wave via LDS
    #pragma unroll
    for (int m = 0; m < 2; ++m)
        #pragma unroll
        for (int j = 0; j < 4; ++j) {
            float s = part[m][j];
            s += __shfl_xor(s, 1);
            s += __shfl_xor(s, 2);
            s += __shfl_xor(s, 4);
            s += __shfl_xor(s, 8);
            if ((lane & 15) == 0)
                rsum[wc][m * 16 + (lane >> 4) * 4 + j] = s;
        }
    __syncthreads();

    // normalize + store
    #pragma unroll
    for (int m = 0; m < 2; ++m) {
        #pragma unroll
        for (int j = 0; j < 4; ++j) {
            const int rloc = m * 16 + (lane >> 4) * 4 + j;
            const float inv = __builtin_amdgcn_rcpf(
                rsum[0][rloc] + rsum[1][rloc] + rsum[2][rloc] + rsum[3][rloc]);
            float* orow = out + (size_t)(rowbase + rloc) * N_DIM;
            #pragma unroll
            for (int n = 0; n < 8; ++n)
                orow[wc * 128 + n * 16 + (lane & 15)] = acc[m][n][j] * inv;
        }
    }
}

extern "C" void kernel_launch(void* const* d_in, const int* in_sizes, int n_in,
                              void* d_out, int out_size, void* d_ws, size_t ws_size,
                              hipStream_t stream) {
    const float* x        = (const float*)d_in[0];
    const float* clusters = (const float*)d_in[1];
    float* out = (float*)d_out;
    unsigned short* cb = (unsigned short*)d_ws;                       // 512*256 bf16 = 256 KB
    float* csq = (float*)((char*)d_ws + (size_t)N_DIM * K_DIM * 2);   // + 2 KB
    prep_clusters<<<N_DIM, K_DIM, 0, stream>>>(clusters, cb, csq);
    cluster_q<<<M_DIM / BM, 256, 0, stream>>>(x, cb, csq, out);
}

// Round 3
// 93.026 us; speedup vs baseline: 1.2637x; 1.0635x over previous
//
#include <hip/hip_runtime.h>
#include <hip/hip_bf16.h>

typedef __attribute__((ext_vector_type(8))) short bf16x8;
typedef __attribute__((ext_vector_type(4))) float f32x4;

#define K_DIM 256
#define N_DIM 512
#define BM 32
#define M_DIM 65536

// round-to-nearest-even fp32 -> bf16 bits
__device__ __forceinline__ unsigned short f2bf(float f) {
    unsigned int u = __float_as_uint(f);
    unsigned int r = (u + 0x7fffu + ((u >> 16) & 1u)) >> 16;
    return (unsigned short)r;
}

// Kernel 1: clusters fp32 -> bf16 (for MFMA) + fp32 row norms.
__global__ __launch_bounds__(256) void prep_clusters(
        const float* __restrict__ clusters,
        unsigned short* __restrict__ cb,
        float* __restrict__ csq) {
    const int row = blockIdx.x;   // 512 rows
    const int t = threadIdx.x;    // 256 = K_DIM
    const float v = clusters[row * K_DIM + t];
    cb[row * K_DIM + t] = f2bf(v);
    float s = v * v;
    #pragma unroll
    for (int m = 1; m < 64; m <<= 1) s += __shfl_xor(s, m);
    __shared__ float red[4];
    if ((t & 63) == 0) red[t >> 6] = s;
    __syncthreads();
    if (t == 0) csq[row] = red[0] + red[1] + red[2] + red[3];
}

// Kernel 2: fused cross-GEMM (bf16 MFMA) + student-t + row normalize.
// Block = 32 rows x ALL 512 cols, 4 waves (one per 128-col group).
// K-loop fully unrolled with ping-pong register double-buffer for B and
// sched_barrier(0) fences so the prefetch cannot be sunk by the scheduler.
__global__ __launch_bounds__(256, 3) void cluster_q(
        const float* __restrict__ x,
        const unsigned short* __restrict__ cb,
        const float* __restrict__ csq,
        float* __restrict__ out) {
    __shared__ __align__(16) unsigned short xa[BM * K_DIM]; // 16 KB bf16, XOR-swizzled
    __shared__ float xsq[BM];
    __shared__ float csql[N_DIM];
    __shared__ float rsum[4][BM];

    const int t = threadIdx.x;
    const int lane = t & 63;
    const int wc = t >> 6;        // wave 0..3 = column group
    const int rowbase = blockIdx.x * BM;

    // stage cluster norms (L2-resident broadcast data)
    for (int i = t; i < N_DIM; i += 256) csql[i] = csq[i];

    // stage x tile: wave w loads rows w+4p as float4 (1 KB/row coalesced),
    // |x|^2 via wave reduce, bf16 store XOR-swizzled.
    #pragma unroll
    for (int p = 0; p < 8; ++p) {
        const int row = wc + p * 4;
        const float4 v = reinterpret_cast<const float4*>(
                             x + (size_t)(rowbase + row) * K_DIM)[lane];
        float s = v.x * v.x + v.y * v.y + v.z * v.z + v.w * v.w;
        #pragma unroll
        for (int m = 1; m < 64; m <<= 1) s += __shfl_xor(s, m);
        if (lane == 0) xsq[row] = s;
        const ushort4 pk = make_ushort4(f2bf(v.x), f2bf(v.y), f2bf(v.z), f2bf(v.w));
        const int swz = (lane * 8) ^ ((row & 7) << 4);
        *reinterpret_cast<ushort4*>(reinterpret_cast<char*>(xa) + row * 512 + swz) = pk;
    }
    __syncthreads();

    f32x4 acc[2][8];
    #pragma unroll
    for (int m = 0; m < 2; ++m)
        #pragma unroll
        for (int n = 0; n < 8; ++n)
            acc[m][n] = (f32x4){0.f, 0.f, 0.f, 0.f};

    // B fragment base for this lane: col = wc*128 + (lane&15), k-half = (lane>>4)*8
    const unsigned short* bbase =
        cb + (size_t)(wc * 128 + (lane & 15)) * K_DIM + (lane >> 4) * 8;

    // ping-pong register double-buffer for B fragments
    bf16x8 bA[8], bB[8];
    #pragma unroll
    for (int n = 0; n < 8; ++n)
        bA[n] = *reinterpret_cast<const bf16x8*>(bbase + n * 16 * K_DIM);

    #pragma unroll
    for (int ks = 0; ks < 8; ++ks) {            // fully unrolled: all guards fold
        const bool even = (ks & 1) == 0;
        // issue next K-step's 8 loads into the other buffer (stay in flight
        // across this step's MFMAs; sched_barrier below pins the order)
        if (ks < 7) {
            #pragma unroll
            for (int n = 0; n < 8; ++n) {
                const bf16x8 v = *reinterpret_cast<const bf16x8*>(
                                     bbase + n * 16 * K_DIM + (ks + 1) * 32);
                if (even) bB[n] = v; else bA[n] = v;
            }
        }
        // A fragments from swizzled LDS
        const int r0 = (lane & 15);
        const int r1 = 16 + (lane & 15);
        const int c0 = (ks * 64 + (lane >> 4) * 16) ^ ((r0 & 7) << 4);
        const int c1 = (ks * 64 + (lane >> 4) * 16) ^ ((r1 & 7) << 4);
        const bf16x8 a0 = *reinterpret_cast<const bf16x8*>(
                              reinterpret_cast<const char*>(xa) + r0 * 512 + c0);
        const bf16x8 a1 = *reinterpret_cast<const bf16x8*>(
                              reinterpret_cast<const char*>(xa) + r1 * 512 + c1);
        __builtin_amdgcn_sched_barrier(0);      // loads may not sink below here
        #pragma unroll
        for (int n = 0; n < 8; ++n) {
            const bf16x8 bc = even ? bA[n] : bB[n];
            acc[0][n] = __builtin_amdgcn_mfma_f32_16x16x32_bf16(a0, bc, acc[0][n], 0, 0, 0);
            acc[1][n] = __builtin_amdgcn_mfma_f32_16x16x32_bf16(a1, bc, acc[1][n], 0, 0, 0);
        }
        __builtin_amdgcn_sched_barrier(0);      // MFMAs may not mix into next loads
    }

    // epilogue: d = |x|^2 + |c|^2 - 2*cross ; q_un = 1/(1+d) (ALPHA=1)
    float xs1[2][4];
    #pragma unroll
    for (int m = 0; m < 2; ++m)
        #pragma unroll
        for (int j = 0; j < 4; ++j)
            xs1[m][j] = 1.f + xsq[m * 16 + (lane >> 4) * 4 + j];

    float part[2][4];
    #pragma unroll
    for (int m = 0; m < 2; ++m)
        #pragma unroll
        for (int j = 0; j < 4; ++j) part[m][j] = 0.f;

    #pragma unroll
    for (int m = 0; m < 2; ++m) {
        #pragma unroll
        for (int n = 0; n < 8; ++n) {
            const float cs = csql[wc * 128 + n * 16 + (lane & 15)];
            #pragma unroll
            for (int j = 0; j < 4; ++j) {
                const float q = __builtin_amdgcn_rcpf(
                                    fmaf(-2.f, acc[m][n][j], xs1[m][j] + cs));
                acc[m][n][j] = q;
                part[m][j] += q;
            }
        }
    }

    // row sums: 16-lane butterfly (cols within wave) then cross-wave via LDS
    #pragma unroll
    for (int m = 0; m < 2; ++m)
        #pragma unroll
        for (int j = 0; j < 4; ++j) {
            float s = part[m][j];
            s += __shfl_xor(s, 1);
            s += __shfl_xor(s, 2);
            s += __shfl_xor(s, 4);
            s += __shfl_xor(s, 8);
            if ((lane & 15) == 0)
                rsum[wc][m * 16 + (lane >> 4) * 4 + j] = s;
        }
    __syncthreads();

    // normalize + store
    #pragma unroll
    for (int m = 0; m < 2; ++m) {
        #pragma unroll
        for (int j = 0; j < 4; ++j) {
            const int rloc = m * 16 + (lane >> 4) * 4 + j;
            const float inv = __builtin_amdgcn_rcpf(
                rsum[0][rloc] + rsum[1][rloc] + rsum[2][rloc] + rsum[3][rloc]);
            float* orow = out + (size_t)(rowbase + rloc) * N_DIM;
            #pragma unroll
            for (int n = 0; n < 8; ++n)
                orow[wc * 128 + n * 16 + (lane & 15)] = acc[m][n][j] * inv;
        }
    }
}

extern "C" void kernel_launch(void* const* d_in, const int* in_sizes, int n_in,
                              void* d_out, int out_size, void* d_ws, size_t ws_size,
                              hipStream_t stream) {
    const float* x        = (const float*)d_in[0];
    const float* clusters = (const float*)d_in[1];
    float* out = (float*)d_out;
    unsigned short* cb = (unsigned short*)d_ws;                       // 512*256 bf16 = 256 KB
    float* csq = (float*)((char*)d_ws + (size_t)N_DIM * K_DIM * 2);   // + 2 KB
    prep_clusters<<<N_DIM, K_DIM, 0, stream>>>(clusters, cb, csq);
    cluster_q<<<M_DIM / BM, 256, 0, stream>>>(x, cb, csq, out);
}

// Round 4
// 62.270 us; speedup vs baseline: 1.8879x; 1.4939x over previous
//
#include <hip/hip_runtime.h>
#include <hip/hip_bf16.h>

typedef __attribute__((ext_vector_type(8))) short bf16x8;
typedef __attribute__((ext_vector_type(4))) float f32x4;

#define K_DIM 256
#define N_DIM 512
#define BM 32
#define M_DIM 65536

// round-to-nearest-even fp32 -> bf16 bits
__device__ __forceinline__ unsigned short f2bf(float f) {
    unsigned int u = __float_as_uint(f);
    unsigned int r = (u + 0x7fffu + ((u >> 16) & 1u)) >> 16;
    return (unsigned short)r;
}

// async global->LDS DMA, 16B per lane. LDS base wave-uniform; global per-lane.
__device__ __forceinline__ void gload_lds16(const unsigned short* g, unsigned short* l) {
    __builtin_amdgcn_global_load_lds(
        (const __attribute__((address_space(1))) void*)g,
        (__attribute__((address_space(3))) void*)l, 16, 0, 0);
}

// Kernel 1: clusters fp32 -> bf16 ARRANGED per-(wc,ks,n,lane) fragment order
// + fp32 row norms.
// arranged[wc][ks][n][lane][8 shorts]:
//   = clusters[wc*128 + n*16 + (lane&15)][ks*32 + (lane>>4)*8 + 0..7]
__global__ __launch_bounds__(256) void prep_clusters(
        const float* __restrict__ clusters,
        unsigned short* __restrict__ cba,
        float* __restrict__ csq) {
    const int row = blockIdx.x;   // 512 rows
    const int t = threadIdx.x;    // 256 = K_DIM
    const float v = clusters[row * K_DIM + t];
    const int wc = row >> 7, n = (row >> 4) & 7, r = row & 15;
    const int ks = t >> 5, kh = (t >> 3) & 3, ko = t & 7;
    cba[(size_t)wc * 32768 + ks * 4096 + n * 512 + (kh * 16 + r) * 8 + ko] = f2bf(v);
    float s = v * v;
    #pragma unroll
    for (int m = 1; m < 64; m <<= 1) s += __shfl_xor(s, m);
    __shared__ float red[4];
    if ((t & 63) == 0) red[t >> 6] = s;
    __syncthreads();
    if (t == 0) csq[row] = red[0] + red[1] + red[2] + red[3];
}

// Kernel 2: fused cross-GEMM + student-t + row normalize.
// Block = 32 rows x 512 cols, 4 waves (wave wc owns cols wc*128..+128).
// Clusters are the MFMA A operand, DMA'd into per-wave-private LDS one
// K-step ahead (no barriers in K-loop). x is the B operand from swizzled LDS.
// Output fragment: lane holds 4 consecutive cluster-cols -> float4 stores.
__global__ __launch_bounds__(256, 3) void cluster_q(
        const float* __restrict__ x,
        const unsigned short* __restrict__ cba,
        const float* __restrict__ csq,
        float* __restrict__ out) {
    __shared__ __align__(16) unsigned short xa[BM * K_DIM];   // 16 KB, XOR-swizzled
    __shared__ __align__(16) unsigned short bB[4 * 4096];     // 4 waves x 8 KB
    __shared__ float xsq[BM];
    __shared__ __align__(16) float csql[N_DIM];
    __shared__ float rsum[4][BM];

    const int t = threadIdx.x;
    const int lane = t & 63;
    const int wc = t >> 6;        // wave 0..3 = column group
    const int rowbase = blockIdx.x * BM;

    unsigned short* myB = bB + wc * 4096;                       // private 8 KB
    const unsigned short* gsrc = cba + (size_t)wc * 32768;      // this wave's slice

    // issue DMA for ks=0 immediately (latency hides under x staging)
    #pragma unroll
    for (int n = 0; n < 8; ++n)
        gload_lds16(gsrc + n * 512 + lane * 8, myB + n * 512);

    // stage cluster norms (L2-resident broadcast data)
    for (int i = t; i < N_DIM; i += 256) csql[i] = csq[i];

    // stage x tile: wave w loads rows w+4p as float4 (1 KB/row coalesced),
    // |x|^2 via wave reduce, bf16 store XOR-swizzled.
    #pragma unroll
    for (int p = 0; p < 8; ++p) {
        const int row = wc + p * 4;
        const float4 v = reinterpret_cast<const float4*>(
                             x + (size_t)(rowbase + row) * K_DIM)[lane];
        float s = v.x * v.x + v.y * v.y + v.z * v.z + v.w * v.w;
        #pragma unroll
        for (int m = 1; m < 64; m <<= 1) s += __shfl_xor(s, m);
        if (lane == 0) xsq[row] = s;
        const ushort4 pk = make_ushort4(f2bf(v.x), f2bf(v.y), f2bf(v.z), f2bf(v.w));
        const int swz = (lane * 8) ^ ((row & 7) << 4);
        *reinterpret_cast<ushort4*>(reinterpret_cast<char*>(xa) + row * 512 + swz) = pk;
    }
    __syncthreads();

    f32x4 acc[2][8];
    #pragma unroll
    for (int m = 0; m < 2; ++m)
        #pragma unroll
        for (int n = 0; n < 8; ++n)
            acc[m][n] = (f32x4){0.f, 0.f, 0.f, 0.f};

    #pragma unroll
    for (int ks = 0; ks < 8; ++ks) {
        // this step's DMA complete
        asm volatile("s_waitcnt vmcnt(0)" ::: "memory");
        __builtin_amdgcn_sched_barrier(0);
        // A (cluster) fragments: lane-linear from private LDS, conflict-free
        bf16x8 a[8];
        #pragma unroll
        for (int n = 0; n < 8; ++n)
            a[n] = *reinterpret_cast<const bf16x8*>(myB + n * 512 + lane * 8);
        // x (B-operand) fragments from swizzled xa
        const int r0 = (lane & 15);
        const int r1 = 16 + (lane & 15);
        const int c0 = (ks * 64 + (lane >> 4) * 16) ^ ((r0 & 7) << 4);
        const int c1 = (ks * 64 + (lane >> 4) * 16) ^ ((r1 & 7) << 4);
        const bf16x8 xm0 = *reinterpret_cast<const bf16x8*>(
                               reinterpret_cast<const char*>(xa) + r0 * 512 + c0);
        const bf16x8 xm1 = *reinterpret_cast<const bf16x8*>(
                               reinterpret_cast<const char*>(xa) + r1 * 512 + c1);
        // all LDS reads done -> buffer is free for next step's DMA (WAR safe)
        asm volatile("s_waitcnt lgkmcnt(0)" ::: "memory");
        __builtin_amdgcn_sched_barrier(0);
        if (ks < 7) {
            #pragma unroll
            for (int n = 0; n < 8; ++n)
                gload_lds16(gsrc + (ks + 1) * 4096 + n * 512 + lane * 8,
                            myB + n * 512);
        }
        __builtin_amdgcn_sched_barrier(0);
        // MFMAs overlap the in-flight DMA
        #pragma unroll
        for (int n = 0; n < 8; ++n) {
            acc[0][n] = __builtin_amdgcn_mfma_f32_16x16x32_bf16(a[n], xm0, acc[0][n], 0, 0, 0);
            acc[1][n] = __builtin_amdgcn_mfma_f32_16x16x32_bf16(a[n], xm1, acc[1][n], 0, 0, 0);
        }
    }

    // epilogue: D[cluster][xrow]; lane: xrow = m*16+(lane&15),
    // cluster cols = wc*128 + n*16 + (lane>>4)*4 + reg (4 consecutive!)
    const float4* csql4 = reinterpret_cast<const float4*>(csql);
    float part[2] = {0.f, 0.f};
    #pragma unroll
    for (int m = 0; m < 2; ++m) {
        const float xs1 = 1.f + xsq[m * 16 + (lane & 15)];
        #pragma unroll
        for (int n = 0; n < 8; ++n) {
            const float4 cs = csql4[wc * 32 + n * 4 + (lane >> 4)];
            f32x4 q;
            q[0] = __builtin_amdgcn_rcpf(fmaf(-2.f, acc[m][n][0], xs1 + cs.x));
            q[1] = __builtin_amdgcn_rcpf(fmaf(-2.f, acc[m][n][1], xs1 + cs.y));
            q[2] = __builtin_amdgcn_rcpf(fmaf(-2.f, acc[m][n][2], xs1 + cs.z));
            q[3] = __builtin_amdgcn_rcpf(fmaf(-2.f, acc[m][n][3], xs1 + cs.w));
            acc[m][n] = q;
            part[m] += (q[0] + q[1]) + (q[2] + q[3]);
        }
    }

    // row sums: reduce across the 4 lane-groups (same xrow), then cross-wave
    #pragma unroll
    for (int m = 0; m < 2; ++m) {
        float s = part[m];
        s += __shfl_xor(s, 16);
        s += __shfl_xor(s, 32);
        if (lane < 16) rsum[wc][m * 16 + lane] = s;
    }
    __syncthreads();

    // normalize + float4 stores
    #pragma unroll
    for (int m = 0; m < 2; ++m) {
        const int b = m * 16 + (lane & 15);
        const float inv = __builtin_amdgcn_rcpf(
            rsum[0][b] + rsum[1][b] + rsum[2][b] + rsum[3][b]);
        float* orow = out + (size_t)(rowbase + b) * N_DIM + wc * 128 + (lane >> 4) * 4;
        #pragma unroll
        for (int n = 0; n < 8; ++n) {
            const f32x4 v = acc[m][n];
            float4 st = make_float4(v[0] * inv, v[1] * inv, v[2] * inv, v[3] * inv);
            *reinterpret_cast<float4*>(orow + n * 16) = st;
        }
    }
}

extern "C" void kernel_launch(void* const* d_in, const int* in_sizes, int n_in,
                              void* d_out, int out_size, void* d_ws, size_t ws_size,
                              hipStream_t stream) {
    const float* x        = (const float*)d_in[0];
    const float* clusters = (const float*)d_in[1];
    float* out = (float*)d_out;
    unsigned short* cba = (unsigned short*)d_ws;                      // 256 KB arranged
    float* csq = (float*)((char*)d_ws + (size_t)N_DIM * K_DIM * 2);   // + 2 KB
    prep_clusters<<<N_DIM, K_DIM, 0, stream>>>(clusters, cba, csq);
    cluster_q<<<M_DIM / BM, 256, 0, stream>>>(x, cba, csq, out);
}

// Round 5
// 60.448 us; speedup vs baseline: 1.9448x; 1.0301x over previous
//
#include <hip/hip_runtime.h>
#include <hip/hip_bf16.h>

typedef __attribute__((ext_vector_type(8))) short bf16x8;
typedef __attribute__((ext_vector_type(4))) float f32x4;

#define K_DIM 256
#define N_DIM 512
#define BM 32
#define M_DIM 65536

// round-to-nearest-even fp32 -> bf16 bits
__device__ __forceinline__ unsigned short f2bf(float f) {
    unsigned int u = __float_as_uint(f);
    unsigned int r = (u + 0x7fffu + ((u >> 16) & 1u)) >> 16;
    return (unsigned short)r;
}

// async global->LDS DMA, 16B per lane. LDS base wave-uniform; global per-lane.
__device__ __forceinline__ void gload_lds16(const unsigned short* g, unsigned short* l) {
    __builtin_amdgcn_global_load_lds(
        (const __attribute__((address_space(1))) void*)g,
        (__attribute__((address_space(3))) void*)l, 16, 0, 0);
}

// Kernel 1: clusters fp32 -> bf16 ARRANGED per-(wc,ks,n,lane) fragment order
// for the 8-wave mapping (wave wc owns 64 cluster cols) + fp32 row norms.
// arranged[wc][ks][n][L][ko] = clusters[wc*64 + n*16 + (L&15)][ks*32 + (L>>4)*8 + ko]
__global__ __launch_bounds__(256) void prep_clusters(
        const float* __restrict__ clusters,
        unsigned short* __restrict__ cba,
        float* __restrict__ csq) {
    const int row = blockIdx.x;   // 512 cluster rows
    const int t = threadIdx.x;    // 256 = K_DIM
    const float v = clusters[row * K_DIM + t];
    const int wc = row >> 6, n = (row >> 4) & 3, r = row & 15;
    const int ks = t >> 5, kh = (t >> 3) & 3, ko = t & 7;
    cba[(size_t)wc * 16384 + ks * 2048 + n * 512 + (kh * 16 + r) * 8 + ko] = f2bf(v);
    float s = v * v;
    #pragma unroll
    for (int m = 1; m < 64; m <<= 1) s += __shfl_xor(s, m);
    __shared__ float red[4];
    if ((t & 63) == 0) red[t >> 6] = s;
    __syncthreads();
    if (t == 0) csq[row] = red[0] + red[1] + red[2] + red[3];
}

// Kernel 2: fused cross-GEMM + student-t + row normalize.
// Block = 32 rows x 512 cols, 8 waves (wave wc owns cols wc*64..+64).
// Clusters (A operand) DMA'd into per-wave-private LDS one K-step ahead,
// no barriers in the K-loop. x (B operand) from XOR-swizzled LDS.
__global__ __launch_bounds__(512, 6) void cluster_q(
        const float* __restrict__ x,
        const unsigned short* __restrict__ cba,
        const float* __restrict__ csq,
        float* __restrict__ out) {
    __shared__ __align__(16) unsigned short xa[BM * K_DIM];   // 16 KB, XOR-swizzled
    __shared__ __align__(16) unsigned short bB[8 * 2048];     // 8 waves x 4 KB
    __shared__ float xsq[BM];
    __shared__ __align__(16) float csql[N_DIM];
    __shared__ float rsum[8][BM];

    const int t = threadIdx.x;
    const int lane = t & 63;
    const int wc = t >> 6;        // wave 0..7 = 64-col group
    const int rowbase = blockIdx.x * BM;

    unsigned short* myB = bB + wc * 2048;                       // private 4 KB
    const unsigned short* gsrc = cba + (size_t)wc * 16384;      // this wave's slice

    // issue DMA for ks=0 immediately (latency hides under x staging)
    #pragma unroll
    for (int n = 0; n < 4; ++n)
        gload_lds16(gsrc + n * 512 + lane * 8, myB + n * 512);

    // stage cluster norms (L2-resident broadcast data)
    if (t < N_DIM) csql[t] = csq[t];

    // stage x tile: wave wc loads rows wc+8p as float4 (1 KB/row coalesced),
    // |x|^2 via wave reduce, bf16 store XOR-swizzled.
    #pragma unroll
    for (int p = 0; p < 4; ++p) {
        const int row = wc + p * 8;
        const float4 v = reinterpret_cast<const float4*>(
                             x + (size_t)(rowbase + row) * K_DIM)[lane];
        float s = v.x * v.x + v.y * v.y + v.z * v.z + v.w * v.w;
        #pragma unroll
        for (int m = 1; m < 64; m <<= 1) s += __shfl_xor(s, m);
        if (lane == 0) xsq[row] = s;
        const ushort4 pk = make_ushort4(f2bf(v.x), f2bf(v.y), f2bf(v.z), f2bf(v.w));
        const int swz = (lane * 8) ^ ((row & 7) << 4);
        *reinterpret_cast<ushort4*>(reinterpret_cast<char*>(xa) + row * 512 + swz) = pk;
    }
    __syncthreads();

    f32x4 acc[2][4];
    #pragma unroll
    for (int m = 0; m < 2; ++m)
        #pragma unroll
        for (int n = 0; n < 4; ++n)
            acc[m][n] = (f32x4){0.f, 0.f, 0.f, 0.f};

    #pragma unroll
    for (int ks = 0; ks < 8; ++ks) {
        // this step's DMA complete
        asm volatile("s_waitcnt vmcnt(0)" ::: "memory");
        __builtin_amdgcn_sched_barrier(0);
        // A (cluster) fragments: lane-linear from private LDS, conflict-free
        bf16x8 a[4];
        #pragma unroll
        for (int n = 0; n < 4; ++n)
            a[n] = *reinterpret_cast<const bf16x8*>(myB + n * 512 + lane * 8);
        // x (B-operand) fragments from swizzled xa
        const int r0 = (lane & 15);
        const int r1 = 16 + (lane & 15);
        const int c0 = (ks * 64 + (lane >> 4) * 16) ^ ((r0 & 7) << 4);
        const int c1 = (ks * 64 + (lane >> 4) * 16) ^ ((r1 & 7) << 4);
        const bf16x8 xm0 = *reinterpret_cast<const bf16x8*>(
                               reinterpret_cast<const char*>(xa) + r0 * 512 + c0);
        const bf16x8 xm1 = *reinterpret_cast<const bf16x8*>(
                               reinterpret_cast<const char*>(xa) + r1 * 512 + c1);
        // all LDS reads done -> buffer free for next step's DMA (WAR safe)
        asm volatile("s_waitcnt lgkmcnt(0)" ::: "memory");
        __builtin_amdgcn_sched_barrier(0);
        if (ks < 7) {
            #pragma unroll
            for (int n = 0; n < 4; ++n)
                gload_lds16(gsrc + (ks + 1) * 2048 + n * 512 + lane * 8,
                            myB + n * 512);
        }
        __builtin_amdgcn_sched_barrier(0);
        // MFMAs overlap the in-flight DMA
        #pragma unroll
        for (int n = 0; n < 4; ++n) {
            acc[0][n] = __builtin_amdgcn_mfma_f32_16x16x32_bf16(a[n], xm0, acc[0][n], 0, 0, 0);
            acc[1][n] = __builtin_amdgcn_mfma_f32_16x16x32_bf16(a[n], xm1, acc[1][n], 0, 0, 0);
        }
    }

    // epilogue: D[cluster][xrow]; lane: xrow = m*16+(lane&15),
    // cluster cols = wc*64 + n*16 + (lane>>4)*4 + reg (4 consecutive)
    const float4* csql4 = reinterpret_cast<const float4*>(csql);
    float part[2] = {0.f, 0.f};
    #pragma unroll
    for (int m = 0; m < 2; ++m) {
        const float xs1 = 1.f + xsq[m * 16 + (lane & 15)];
        #pragma unroll
        for (int n = 0; n < 4; ++n) {
            const float4 cs = csql4[wc * 16 + n * 4 + (lane >> 4)];
            f32x4 q;
            q[0] = __builtin_amdgcn_rcpf(fmaf(-2.f, acc[m][n][0], xs1 + cs.x));
            q[1] = __builtin_amdgcn_rcpf(fmaf(-2.f, acc[m][n][1], xs1 + cs.y));
            q[2] = __builtin_amdgcn_rcpf(fmaf(-2.f, acc[m][n][2], xs1 + cs.z));
            q[3] = __builtin_amdgcn_rcpf(fmaf(-2.f, acc[m][n][3], xs1 + cs.w));
            acc[m][n] = q;
            part[m] += (q[0] + q[1]) + (q[2] + q[3]);
        }
    }

    // row sums: reduce across the 4 lane-groups (same xrow), then cross-wave
    #pragma unroll
    for (int m = 0; m < 2; ++m) {
        float s = part[m];
        s += __shfl_xor(s, 16);
        s += __shfl_xor(s, 32);
        if (lane < 16) rsum[wc][m * 16 + lane] = s;
    }
    __syncthreads();

    // normalize + float4 stores
    #pragma unroll
    for (int m = 0; m < 2; ++m) {
        const int b = m * 16 + (lane & 15);
        const float inv = __builtin_amdgcn_rcpf(
            ((rsum[0][b] + rsum[1][b]) + (rsum[2][b] + rsum[3][b])) +
            ((rsum[4][b] + rsum[5][b]) + (rsum[6][b] + rsum[7][b])));
        float* orow = out + (size_t)(rowbase + b) * N_DIM + wc * 64 + (lane >> 4) * 4;
        #pragma unroll
        for (int n = 0; n < 4; ++n) {
            const f32x4 v = acc[m][n];
            float4 st = make_float4(v[0] * inv, v[1] * inv, v[2] * inv, v[3] * inv);
            *reinterpret_cast<float4*>(orow + n * 16) = st;
        }
    }
}

extern "C" void kernel_launch(void* const* d_in, const int* in_sizes, int n_in,
                              void* d_out, int out_size, void* d_ws, size_t ws_size,
                              hipStream_t stream) {
    const float* x        = (const float*)d_in[0];
    const float* clusters = (const float*)d_in[1];
    float* out = (float*)d_out;
    unsigned short* cba = (unsigned short*)d_ws;                      // 256 KB arranged
    float* csq = (float*)((char*)d_ws + (size_t)N_DIM * K_DIM * 2);   // + 2 KB
    prep_clusters<<<N_DIM, K_DIM, 0, stream>>>(clusters, cba, csq);
    cluster_q<<<M_DIM / BM, 512, 0, stream>>>(x, cba, csq, out);
}

// Round 6
// 53.382 us; speedup vs baseline: 2.2022x; 1.1324x over previous
//
#include <hip/hip_runtime.h>
#include <hip/hip_bf16.h>

typedef __attribute__((ext_vector_type(8))) short bf16x8;
typedef __attribute__((ext_vector_type(4))) float f32x4;

#define K_DIM 256
#define N_DIM 512
#define BM 32
#define M_DIM 65536
#define TPB 8                        // x-tiles per block
#define GRID (M_DIM / BM / TPB)      // 256 blocks = 1 per CU

// round-to-nearest-even fp32 -> bf16 bits
__device__ __forceinline__ unsigned short f2bf(float f) {
    unsigned int u = __float_as_uint(f);
    unsigned int r = (u + 0x7fffu + ((u >> 16) & 1u)) >> 16;
    return (unsigned short)r;
}

// Kernel 1: clusters fp32 -> bf16 ARRANGED per-(wc,ks,n,lane) fragment order
// (wave wc owns 64 cluster cols) + fp32 row norms.
// arranged[wc][ks][n][L][ko] = clusters[wc*64 + n*16 + (L&15)][ks*32 + (L>>4)*8 + ko]
__global__ __launch_bounds__(256) void prep_clusters(
        const float* __restrict__ clusters,
        unsigned short* __restrict__ cba,
        float* __restrict__ csq) {
    const int row = blockIdx.x;   // 512 cluster rows
    const int t = threadIdx.x;    // 256 = K_DIM
    const float v = clusters[row * K_DIM + t];
    const int wc = row >> 6, n = (row >> 4) & 3, r = row & 15;
    const int ks = t >> 5, kh = (t >> 3) & 3, ko = t & 7;
    cba[(size_t)wc * 16384 + ks * 2048 + n * 512 + (kh * 16 + r) * 8 + ko] = f2bf(v);
    float s = v * v;
    #pragma unroll
    for (int m = 1; m < 64; m <<= 1) s += __shfl_xor(s, m);
    __shared__ float red[4];
    if ((t & 63) == 0) red[t >> 6] = s;
    __syncthreads();
    if (t == 0) csq[row] = red[0] + red[1] + red[2] + red[3];
}

// Kernel 2: clusters live in REGISTERS (128 VGPR/wave, loaded once);
// x streamed through LDS, 8 tiles of 32 rows per block. K-loop has zero
// global-memory dependency. Next tile's x loads issued under the K-loop.
__global__ __launch_bounds__(512, 2) void cluster_q(
        const float* __restrict__ x,
        const unsigned short* __restrict__ cba,
        const float* __restrict__ csq,
        float* __restrict__ out) {
    __shared__ __align__(16) unsigned short xa[BM * K_DIM];   // 16 KB, XOR-swizzled
    __shared__ float xsq[BM];
    __shared__ __align__(16) float csql[N_DIM];
    __shared__ float rsum[8][BM];

    const int t = threadIdx.x;
    const int lane = t & 63;
    const int wc = t >> 6;        // wave 0..7 = 64-col cluster group

    // ---- prologue: this wave's cluster slice -> registers, permanently ----
    const unsigned short* gsrc = cba + (size_t)wc * 16384;
    bf16x8 breg[8][4];
    #pragma unroll
    for (int ks = 0; ks < 8; ++ks)
        #pragma unroll
        for (int n = 0; n < 4; ++n)
            breg[ks][n] = *reinterpret_cast<const bf16x8*>(
                              gsrc + ks * 2048 + n * 512 + lane * 8);

    csql[t] = csq[t];   // t in [0,512)

    const size_t base = (size_t)blockIdx.x * (TPB * BM);

    // preload tile 0's x rows (wave wc owns rows wc, wc+8, wc+16, wc+24)
    float4 xr0, xr1, xr2, xr3;
    {
        const float4* xp = reinterpret_cast<const float4*>(x + (base + wc) * K_DIM);
        xr0 = xp[lane];                 // row wc       (+p*8 rows = +p*512 float4)
        xr1 = xp[512 + lane];
        xr2 = xp[1024 + lane];
        xr3 = xp[1536 + lane];
    }

    for (int it = 0; it < TPB; ++it) {
        const size_t rowbase = base + (size_t)it * BM;

        // ---- stage x tile: bf16-convert to swizzled LDS + |x|^2 ----
        const float4 vv[4] = {xr0, xr1, xr2, xr3};
        #pragma unroll
        for (int p = 0; p < 4; ++p) {
            const int row = wc + p * 8;
            const float4 v = vv[p];
            float s = v.x * v.x + v.y * v.y + v.z * v.z + v.w * v.w;
            #pragma unroll
            for (int m = 1; m < 64; m <<= 1) s += __shfl_xor(s, m);
            if (lane == 0) xsq[row] = s;
            const ushort4 pk = make_ushort4(f2bf(v.x), f2bf(v.y), f2bf(v.z), f2bf(v.w));
            const int swz = (lane * 8) ^ ((row & 7) << 4);
            *reinterpret_cast<ushort4*>(reinterpret_cast<char*>(xa) + row * 512 + swz) = pk;
        }
        __syncthreads();

        // ---- issue next tile's x loads; they fly under the K-loop ----
        if (it + 1 < TPB) {
            const float4* xp = reinterpret_cast<const float4*>(
                                   x + (rowbase + BM + wc) * K_DIM);
            xr0 = xp[lane];
            xr1 = xp[512 + lane];
            xr2 = xp[1024 + lane];
            xr3 = xp[1536 + lane];
        }
        __builtin_amdgcn_sched_barrier(0);   // pin load issue above the K-loop

        // ---- K-loop: pure registers x LDS ----
        f32x4 acc[2][4];
        #pragma unroll
        for (int m = 0; m < 2; ++m)
            #pragma unroll
            for (int n = 0; n < 4; ++n)
                acc[m][n] = (f32x4){0.f, 0.f, 0.f, 0.f};

        #pragma unroll
        for (int ks = 0; ks < 8; ++ks) {
            const int r0 = (lane & 15);
            const int r1 = 16 + (lane & 15);
            const int c0 = (ks * 64 + (lane >> 4) * 16) ^ ((r0 & 7) << 4);
            const int c1 = (ks * 64 + (lane >> 4) * 16) ^ ((r1 & 7) << 4);
            const bf16x8 xm0 = *reinterpret_cast<const bf16x8*>(
                                   reinterpret_cast<const char*>(xa) + r0 * 512 + c0);
            const bf16x8 xm1 = *reinterpret_cast<const bf16x8*>(
                                   reinterpret_cast<const char*>(xa) + r1 * 512 + c1);
            #pragma unroll
            for (int n = 0; n < 4; ++n) {
                acc[0][n] = __builtin_amdgcn_mfma_f32_16x16x32_bf16(breg[ks][n], xm0, acc[0][n], 0, 0, 0);
                acc[1][n] = __builtin_amdgcn_mfma_f32_16x16x32_bf16(breg[ks][n], xm1, acc[1][n], 0, 0, 0);
            }
        }

        // ---- epilogue: q = 1/(1+d), row sums, normalize, store ----
        const float4* csql4 = reinterpret_cast<const float4*>(csql);
        float part[2] = {0.f, 0.f};
        #pragma unroll
        for (int m = 0; m < 2; ++m) {
            const float xs1 = 1.f + xsq[m * 16 + (lane & 15)];
            #pragma unroll
            for (int n = 0; n < 4; ++n) {
                const float4 cs = csql4[wc * 16 + n * 4 + (lane >> 4)];
                f32x4 q;
                q[0] = __builtin_amdgcn_rcpf(fmaf(-2.f, acc[m][n][0], xs1 + cs.x));
                q[1] = __builtin_amdgcn_rcpf(fmaf(-2.f, acc[m][n][1], xs1 + cs.y));
                q[2] = __builtin_amdgcn_rcpf(fmaf(-2.f, acc[m][n][2], xs1 + cs.z));
                q[3] = __builtin_amdgcn_rcpf(fmaf(-2.f, acc[m][n][3], xs1 + cs.w));
                acc[m][n] = q;
                part[m] += (q[0] + q[1]) + (q[2] + q[3]);
            }
        }
        #pragma unroll
        for (int m = 0; m < 2; ++m) {
            float s = part[m];
            s += __shfl_xor(s, 16);
            s += __shfl_xor(s, 32);
            if (lane < 16) rsum[wc][m * 16 + lane] = s;
        }
        __syncthreads();

        #pragma unroll
        for (int m = 0; m < 2; ++m) {
            const int b = m * 16 + (lane & 15);
            const float inv = __builtin_amdgcn_rcpf(
                ((rsum[0][b] + rsum[1][b]) + (rsum[2][b] + rsum[3][b])) +
                ((rsum[4][b] + rsum[5][b]) + (rsum[6][b] + rsum[7][b])));
            float* orow = out + (rowbase + b) * N_DIM + wc * 64 + (lane >> 4) * 4;
            #pragma unroll
            for (int n = 0; n < 4; ++n) {
                const f32x4 v = acc[m][n];
                float4 st = make_float4(v[0] * inv, v[1] * inv, v[2] * inv, v[3] * inv);
                *reinterpret_cast<float4*>(orow + n * 16) = st;
            }
        }
        // next iteration's xa/xsq/rsum writes are separated from this tile's
        // reads by the staging __syncthreads() at loop top
    }
}

extern "C" void kernel_launch(void* const* d_in, const int* in_sizes, int n_in,
                              void* d_out, int out_size, void* d_ws, size_t ws_size,
                              hipStream_t stream) {
    const float* x        = (const float*)d_in[0];
    const float* clusters = (const float*)d_in[1];
    float* out = (float*)d_out;
    unsigned short* cba = (unsigned short*)d_ws;                      // 256 KB arranged
    float* csq = (float*)((char*)d_ws + (size_t)N_DIM * K_DIM * 2);   // + 2 KB
    prep_clusters<<<N_DIM, K_DIM, 0, stream>>>(clusters, cba, csq);
    cluster_q<<<GRID, 512, 0, stream>>>(x, cba, csq, out);
}

// Round 7
// 50.573 us; speedup vs baseline: 2.3246x; 1.0555x over previous
//
#include <hip/hip_runtime.h>
#include <hip/hip_bf16.h>

typedef __attribute__((ext_vector_type(8))) short bf16x8;
typedef __attribute__((ext_vector_type(4))) float f32x4;

#define K_DIM 256
#define N_DIM 512
#define BM 32
#define M_DIM 65536
#define TPB 8                        // x-tiles per block
#define GRID (M_DIM / BM / TPB)      // 256 blocks = 1 per CU

// round-to-nearest-even fp32 -> bf16 bits
__device__ __forceinline__ unsigned short f2bf(float f) {
    unsigned int u = __float_as_uint(f);
    unsigned int r = (u + 0x7fffu + ((u >> 16) & 1u)) >> 16;
    return (unsigned short)r;
}

// barrier that does NOT drain global stores/loads: LDS-visibility only.
// (__syncthreads would emit s_waitcnt vmcnt(0) and serialize store drain)
__device__ __forceinline__ void barrier_lds() {
    asm volatile("s_waitcnt lgkmcnt(0)" ::: "memory");
    __builtin_amdgcn_s_barrier();
}

// Kernel 1: clusters fp32 -> bf16 ARRANGED per-(wc,ks,n,lane) fragment order
// (wave wc owns 64 cluster cols) + fp32 row norms.
// arranged[wc][ks][n][L][ko] = clusters[wc*64 + n*16 + (L&15)][ks*32 + (L>>4)*8 + ko]
__global__ __launch_bounds__(256) void prep_clusters(
        const float* __restrict__ clusters,
        unsigned short* __restrict__ cba,
        float* __restrict__ csq) {
    const int row = blockIdx.x;   // 512 cluster rows
    const int t = threadIdx.x;    // 256 = K_DIM
    const float v = clusters[row * K_DIM + t];
    const int wc = row >> 6, n = (row >> 4) & 3, r = row & 15;
    const int ks = t >> 5, kh = (t >> 3) & 3, ko = t & 7;
    cba[(size_t)wc * 16384 + ks * 2048 + n * 512 + (kh * 16 + r) * 8 + ko] = f2bf(v);
    float s = v * v;
    #pragma unroll
    for (int m = 1; m < 64; m <<= 1) s += __shfl_xor(s, m);
    __shared__ float red[4];
    if ((t & 63) == 0) red[t >> 6] = s;
    __syncthreads();
    if (t == 0) csq[row] = red[0] + red[1] + red[2] + red[3];
}

// Kernel 2: clusters permanently in registers (128 VGPR/wave); x streamed
// through DOUBLE-BUFFERED swizzled LDS; ONE lgkm-only barrier per tile —
// global stores and prefetch loads stay in flight across barriers.
__global__ __launch_bounds__(512, 2) void cluster_q(
        const float* __restrict__ x,
        const unsigned short* __restrict__ cba,
        const float* __restrict__ csq,
        float* __restrict__ out) {
    __shared__ __align__(16) unsigned short xa[2][BM * K_DIM]; // 2 x 16 KB, XOR-swizzled
    __shared__ float xsq[2][BM];
    __shared__ __align__(16) float csql[N_DIM];
    __shared__ float rsum[2][8][BM];

    const int t = threadIdx.x;
    const int lane = t & 63;
    const int wc = t >> 6;        // wave 0..7 = 64-col cluster group

    // ---- prologue: this wave's cluster slice -> registers, permanently ----
    const unsigned short* gsrc = cba + (size_t)wc * 16384;
    bf16x8 breg[8][4];
    #pragma unroll
    for (int ks = 0; ks < 8; ++ks)
        #pragma unroll
        for (int n = 0; n < 4; ++n)
            breg[ks][n] = *reinterpret_cast<const bf16x8*>(
                              gsrc + ks * 2048 + n * 512 + lane * 8);

    csql[t] = csq[t];   // t in [0,512)

    const size_t base = (size_t)blockIdx.x * (TPB * BM);

    float4 xr0, xr1, xr2, xr3;
    // load tile 0 (wave wc owns rows wc, wc+8, wc+16, wc+24)
    {
        const float4* xp = reinterpret_cast<const float4*>(x + (base + wc) * K_DIM);
        xr0 = xp[lane]; xr1 = xp[512 + lane]; xr2 = xp[1024 + lane]; xr3 = xp[1536 + lane];
    }
    // stage tile 0 into buffer 0
    {
        const float4 vv[4] = {xr0, xr1, xr2, xr3};
        #pragma unroll
        for (int p = 0; p < 4; ++p) {
            const int row = wc + p * 8;
            const float4 v = vv[p];
            float s = v.x * v.x + v.y * v.y + v.z * v.z + v.w * v.w;
            #pragma unroll
            for (int m = 1; m < 64; m <<= 1) s += __shfl_xor(s, m);
            if (lane == 0) xsq[0][row] = s;
            const ushort4 pk = make_ushort4(f2bf(v.x), f2bf(v.y), f2bf(v.z), f2bf(v.w));
            const int swz = (lane * 8) ^ ((row & 7) << 4);
            *reinterpret_cast<ushort4*>(
                reinterpret_cast<char*>(xa[0]) + row * 512 + swz) = pk;
        }
    }
    // issue tile 1's loads (fly across the barrier; staged at iteration 0)
    {
        const float4* xp = reinterpret_cast<const float4*>(x + (base + BM + wc) * K_DIM);
        xr0 = xp[lane]; xr1 = xp[512 + lane]; xr2 = xp[1024 + lane]; xr3 = xp[1536 + lane];
    }
    barrier_lds();

    for (int it = 0; it < TPB; ++it) {
        const int cur = it & 1, nxt = cur ^ 1;
        const size_t rowbase = base + (size_t)it * BM;

        // ---- stage tile it+1 into buffer nxt (xr vmcnt-waited here; its
        //      loads had a full tile of cover) ----
        if (it + 1 < TPB) {
            const float4 vv[4] = {xr0, xr1, xr2, xr3};
            #pragma unroll
            for (int p = 0; p < 4; ++p) {
                const int row = wc + p * 8;
                const float4 v = vv[p];
                float s = v.x * v.x + v.y * v.y + v.z * v.z + v.w * v.w;
                #pragma unroll
                for (int m = 1; m < 64; m <<= 1) s += __shfl_xor(s, m);
                if (lane == 0) xsq[nxt][row] = s;
                const ushort4 pk = make_ushort4(f2bf(v.x), f2bf(v.y), f2bf(v.z), f2bf(v.w));
                const int swz = (lane * 8) ^ ((row & 7) << 4);
                *reinterpret_cast<ushort4*>(
                    reinterpret_cast<char*>(xa[nxt]) + row * 512 + swz) = pk;
            }
        }
        // ---- issue tile it+2's loads ----
        if (it + 2 < TPB) {
            const float4* xp = reinterpret_cast<const float4*>(
                                   x + (rowbase + 2 * BM + wc) * K_DIM);
            xr0 = xp[lane]; xr1 = xp[512 + lane]; xr2 = xp[1024 + lane]; xr3 = xp[1536 + lane];
        }
        __builtin_amdgcn_sched_barrier(0);   // pin staging+load issue above K-loop

        // ---- K-loop: registers x LDS[cur], zero global dependency ----
        f32x4 acc[2][4];
        #pragma unroll
        for (int m = 0; m < 2; ++m)
            #pragma unroll
            for (int n = 0; n < 4; ++n)
                acc[m][n] = (f32x4){0.f, 0.f, 0.f, 0.f};

        const char* xab = reinterpret_cast<const char*>(xa[cur]);
        #pragma unroll
        for (int ks = 0; ks < 8; ++ks) {
            const int r0 = (lane & 15);
            const int r1 = 16 + (lane & 15);
            const int c0 = (ks * 64 + (lane >> 4) * 16) ^ ((r0 & 7) << 4);
            const int c1 = (ks * 64 + (lane >> 4) * 16) ^ ((r1 & 7) << 4);
            const bf16x8 xm0 = *reinterpret_cast<const bf16x8*>(xab + r0 * 512 + c0);
            const bf16x8 xm1 = *reinterpret_cast<const bf16x8*>(xab + r1 * 512 + c1);
            #pragma unroll
            for (int n = 0; n < 4; ++n) {
                acc[0][n] = __builtin_amdgcn_mfma_f32_16x16x32_bf16(breg[ks][n], xm0, acc[0][n], 0, 0, 0);
                acc[1][n] = __builtin_amdgcn_mfma_f32_16x16x32_bf16(breg[ks][n], xm1, acc[1][n], 0, 0, 0);
            }
        }

        // ---- epilogue: q = 1/(1+d), row sums, normalize, store ----
        const float4* csql4 = reinterpret_cast<const float4*>(csql);
        float part[2] = {0.f, 0.f};
        #pragma unroll
        for (int m = 0; m < 2; ++m) {
            const float xs1 = 1.f + xsq[cur][m * 16 + (lane & 15)];
            #pragma unroll
            for (int n = 0; n < 4; ++n) {
                const float4 cs = csql4[wc * 16 + n * 4 + (lane >> 4)];
                f32x4 q;
                q[0] = __builtin_amdgcn_rcpf(fmaf(-2.f, acc[m][n][0], xs1 + cs.x));
                q[1] = __builtin_amdgcn_rcpf(fmaf(-2.f, acc[m][n][1], xs1 + cs.y));
                q[2] = __builtin_amdgcn_rcpf(fmaf(-2.f, acc[m][n][2], xs1 + cs.z));
                q[3] = __builtin_amdgcn_rcpf(fmaf(-2.f, acc[m][n][3], xs1 + cs.w));
                acc[m][n] = q;
                part[m] += (q[0] + q[1]) + (q[2] + q[3]);
            }
        }
        #pragma unroll
        for (int m = 0; m < 2; ++m) {
            float s = part[m];
            s += __shfl_xor(s, 16);
            s += __shfl_xor(s, 32);
            if (lane < 16) rsum[cur][wc][m * 16 + lane] = s;
        }
        // the ONLY barrier per tile: lgkm-only (stores stay in flight).
        // Also seals: staging writes of buffer nxt (above) happen-before
        // every wave's K-loop reads of nxt at iteration it+1.
        barrier_lds();

        #pragma unroll
        for (int m = 0; m < 2; ++m) {
            const int b = m * 16 + (lane & 15);
            const float inv = __builtin_amdgcn_rcpf(
                ((rsum[cur][0][b] + rsum[cur][1][b]) + (rsum[cur][2][b] + rsum[cur][3][b])) +
                ((rsum[cur][4][b] + rsum[cur][5][b]) + (rsum[cur][6][b] + rsum[cur][7][b])));
            float* orow = out + (rowbase + b) * N_DIM + wc * 64 + (lane >> 4) * 4;
            #pragma unroll
            for (int n = 0; n < 4; ++n) {
                const f32x4 v = acc[m][n];
                float4 st = make_float4(v[0] * inv, v[1] * inv, v[2] * inv, v[3] * inv);
                *reinterpret_cast<float4*>(orow + n * 16) = st;
            }
        }
        // no trailing barrier: rsum is double-buffered, xa[cur] is re-staged
        // only at iteration it+1 whose staging follows this wave's own reads;
        // cross-wave xa[cur] reads all completed before barrier above.
    }
}

extern "C" void kernel_launch(void* const* d_in, const int* in_sizes, int n_in,
                              void* d_out, int out_size, void* d_ws, size_t ws_size,
                              hipStream_t stream) {
    const float* x        = (const float*)d_in[0];
    const float* clusters = (const float*)d_in[1];
    float* out = (float*)d_out;
    unsigned short* cba = (unsigned short*)d_ws;                      // 256 KB arranged
    float* csq = (float*)((char*)d_ws + (size_t)N_DIM * K_DIM * 2);   // + 2 KB
    prep_clusters<<<N_DIM, K_DIM, 0, stream>>>(clusters, cba, csq);
    cluster_q<<<GRID, 512, 0, stream>>>(x, cba, csq, out);
}